// Round 1
// 285.536 us; speedup vs baseline: 1.1017x; 1.1017x over previous
//
#include <hip/hip_runtime.h>
#include <math.h>

typedef __attribute__((ext_vector_type(8))) short  short8;   // 8 bf16 (4 VGPRs) - MFMA A/B frag
typedef __attribute__((ext_vector_type(4))) float  floatx4;  // MFMA C/D frag
typedef __attribute__((ext_vector_type(2))) float  float2v;  // packed pair (v_pk_add_f32)
typedef __attribute__((ext_vector_type(4))) unsigned int uintx4; // 16B vector load

#define NLOCI 8
#define VOCAB 512
#define DDIM  256
#define HID   512
#define NSAMP (8192 * 16)

__device__ __forceinline__ float bitsf(unsigned int u) {
    union { unsigned int u; float f; } c; c.u = u; return c.f;
}
__device__ __forceinline__ unsigned short f2bf(float f) {  // RNE (used in k1, cold path)
    union { float f; unsigned int u; } c; c.f = f;
    unsigned int u = c.u;
    return (unsigned short)((u + 0x7FFFu + ((u >> 16) & 1u)) >> 16);
}
__device__ __forceinline__ unsigned short f2bf_fast(float f) {  // round-half-up, 2 ops
    union { float f; unsigned int u; } c; c.f = f;
    return (unsigned short)((c.u + 0x8000u) >> 16);
}
// tanh-form GELU via exp2+rcp; |diff vs erf-GELU| ~3e-4 << threshold.
__device__ __forceinline__ float gelu_fast(float x) {
    float t = x * x;
    float y = x * __builtin_fmaf(0.035677408f, t, 0.79788456f);
    float e = __builtin_amdgcn_exp2f(y * 2.8853901f);
    float r = __builtin_amdgcn_rcpf(e + 1.0f);
    return x - x * r;
}
// async 16B/lane global->LDS DMA (lane i lands at lds_base + i*16)
__device__ __forceinline__ void async_copy16(const void* g, void* l) {
    __builtin_amdgcn_global_load_lds(
        (const __attribute__((address_space(1))) unsigned int*)g,
        (__attribute__((address_space(3))) unsigned int*)l, 16, 0, 0);
}

// ---------------------------------------------------------------------------
// Kernel 1: Tp[l] = tables[l] (512x256) @ W1[l*256:(l+1)*256] (256x512), bf16.
// b1 folded into locus 0. XOR-swizzled LDS tiles (32 chunks of 16B per row):
//   element (row, k) lives at row*256 + ((k>>3) ^ (row&31))*8 + (k&7)  [shorts]
// grid = 8 loci * 8 vblocks * 8 nblocks = 512 blocks, 256 threads.
// ---------------------------------------------------------------------------
__global__ __launch_bounds__(256) void k_fuse_tables(
    const float* __restrict__ tables,   // [8][512][256] f32
    const float* __restrict__ W1,       // [2048][512] f32
    const float* __restrict__ b1,       // [512] f32
    unsigned short* __restrict__ Tp)    // [8][512][512] bf16
{
    const int l  = blockIdx.x >> 6;
    const int v0 = ((blockIdx.x >> 3) & 7) * 64;
    const int n0 = (blockIdx.x & 7) * 64;

    __shared__ unsigned short a_lds[64 * 256];   // 32 KB, swizzled
    __shared__ unsigned short bt_lds[64 * 256];  // 32 KB, swizzled (bt[n][k])

    const int t = threadIdx.x;

    // ---- stage A (tables tile): float4 coalesced loads, conflict-free writes
    {
        const float* asrc = tables + (l * 512 + v0) * 256;
#pragma unroll
        for (int i = 0; i < 16; ++i) {
            int flat = i * 1024 + t * 4;
            int row = flat >> 8, k = flat & 255;
            float4 v = *(const float4*)(asrc + flat);
            ushort4 pk4;
            pk4.x = f2bf(v.x); pk4.y = f2bf(v.y); pk4.z = f2bf(v.z); pk4.w = f2bf(v.w);
            int chunkX = (k >> 3) ^ (row & 31);
            *(ushort4*)(a_lds + row * 256 + chunkX * 8 + (k & 7)) = pk4;
        }
    }
    // ---- stage B^T: bt[n][k] = bf16(W1[l*256+k][n0+n])
    {
        const int n = t & 63;
        const int kq = (t >> 6) * 64;
        const float* bsrc = W1 + (l * 256) * 512 + n0 + n;
#pragma unroll
        for (int i = 0; i < 8; ++i) {
            int k0 = kq + i * 8;
            short8 pk8;
#pragma unroll
            for (int j = 0; j < 8; ++j)
                pk8[j] = (short)f2bf(bsrc[(k0 + j) * 512]);
            int chunkX = (k0 >> 3) ^ (n & 31);
            *(short8*)(bt_lds + n * 256 + chunkX * 8) = pk8;
        }
    }
    __syncthreads();

    const int wave = t >> 6, lane = t & 63;
    const int p = lane & 15, q = lane >> 4;
    const int arow = wave * 16 + p;

    floatx4 acc[4];
#pragma unroll
    for (int nt = 0; nt < 4; ++nt) acc[nt] = (floatx4){0.f, 0.f, 0.f, 0.f};

#pragma unroll
    for (int kc = 0; kc < 8; ++kc) {
        int cq = kc * 4 + q;
        short8 afrag = *(const short8*)(a_lds + arow * 256 + (cq ^ (arow & 31)) * 8);
#pragma unroll
        for (int nt = 0; nt < 4; ++nt) {
            int brow = nt * 16 + p;
            short8 bfrag = *(const short8*)(bt_lds + brow * 256 + (cq ^ (brow & 31)) * 8);
            acc[nt] = __builtin_amdgcn_mfma_f32_16x16x32_bf16(afrag, bfrag, acc[nt], 0, 0, 0);
        }
    }

    // D: row(M=vocab) = q*4 + r, col(N) = nt*16 + p; fold b1 at l==0
#pragma unroll
    for (int nt = 0; nt < 4; ++nt) {
        int col = n0 + nt * 16 + p;
        float badd = (l == 0) ? b1[col] : 0.0f;
#pragma unroll
        for (int r = 0; r < 4; ++r) {
            int row = v0 + wave * 16 + q * 4 + r;
            Tp[(l * 512 + row) * 512 + col] = f2bf(acc[nt][r] + badd);
        }
    }
}

// ---------------------------------------------------------------------------
// Kernel 1b: LDS-tiled transpose+cvt: out[c][r] = bf16(in[r][c]), in [R][C] f32.
// ---------------------------------------------------------------------------
__global__ __launch_bounds__(256) void k_transpose_cvt(
    const float* __restrict__ in, unsigned short* __restrict__ out, int R, int C)
{
    __shared__ float tile[64 * 65];
    const int t = threadIdx.x;
    const int r0 = blockIdx.x * 64, c0 = blockIdx.y * 64;

#pragma unroll
    for (int i = 0; i < 16; ++i) {
        int flat = i * 256 + t;
        int rr = flat >> 6, cc = flat & 63;
        tile[rr * 65 + cc] = in[(r0 + rr) * C + c0 + cc];
    }
    __syncthreads();
#pragma unroll
    for (int i = 0; i < 8; ++i) {
        int flat = i * 256 + t;
        int cc = flat >> 5, rp = (flat & 31) * 2;
        ushort2 v;
        v.x = f2bf(tile[rp * 65 + cc]);
        v.y = f2bf(tile[(rp + 1) * 65 + cc]);
        *(ushort2*)(out + (c0 + cc) * R + r0 + rp) = v;
    }
}

// ---------------------------------------------------------------------------
// Kernel 2: fused gather + GELU + (h @ W2 + b2)
// RESTRUCTURED: counted-vmcnt pipeline (T3/T4) + distance-1 gather prefetch
// (T14). Raw s_barrier + manual waitcnt so prefetched gathers stay in flight
// across barriers; DMA latency hides under the afrag VALU phase; gather
// latency hides under one full k-slice of work.
//   per even slice s (kb = s/2):
//     lgkmcnt(0); s_barrier            // tile kb-1 consumed by all waves
//     DMA(kb) x8                       // vmcnt += 8
//     issue gathers slice s+1  x8      // vmcnt += 8   (order pinned by fences)
//     afrag(slice s)                   // consumes slice-s gathers (oldest)
//     s_waitcnt vmcnt(8); s_barrier    // own DMA landed; 8 gathers STILL flying
//     16x MFMA from LDS
// block = 256 threads (4 waves), 64 samples/block, LDS 32 KB,
// __launch_bounds__(256,3): ~168-VGPR budget for ga/gb prefetch regs.
// ---------------------------------------------------------------------------
__global__ __launch_bounds__(256, 3) void k_main(
    const int* __restrict__ hap,              // [131072][8] int32
    const unsigned short* __restrict__ Tp,    // [8][512][512] bf16 (b1 folded)
    const unsigned short* __restrict__ W2t,   // [256][512] bf16
    const float* __restrict__ b2,             // [256] f32
    float* __restrict__ out)                  // [131072][256] f32
{
    // w2 tile: [n=256][k_local=64] shorts; element (n,k) at
    //   n*64 + ((k>>3) ^ (n&7))*8 + (k&7)
    __shared__ unsigned short w2_lds[256 * 64];  // 32 KB exactly

    const int t = threadIdx.x;
    const int wave = t >> 6, lane = t & 63;
    const int p = lane & 15, q = lane >> 4;
    const int m_base = blockIdx.x * 64 + wave * 16;

    // ---- 32-bit byte offsets of the 8 gathered Tp rows (q*16 folded in)
    unsigned int goff[8];
    {
        const uintx4* hp = (const uintx4*)(hap + (m_base + p) * 8);
        uintx4 h0 = hp[0], h1 = hp[1];
#pragma unroll
        for (int l = 0; l < 4; ++l) {
            goff[l]     = (unsigned)(l)     * 524288u + (h0[l] & 511u) * 1024u + (unsigned)(q * 16);
            goff[l + 4] = (unsigned)(l + 4) * 524288u + (h1[l] & 511u) * 1024u + (unsigned)(q * 16);
        }
    }
    const char* Tpc = (const char*)Tp;

    // ---- DMA lane mapping for W2 staging (matches swizzle exactly)
    const int drow = lane >> 3;
    const int j_sw = (lane & 7) ^ (drow & 7);
    const unsigned short* wsrc = W2t + (wave * 64 + drow) * 512 + j_sw * 8;
    const int p7 = p & 7;

    floatx4 acc[16];
#pragma unroll
    for (int nt = 0; nt < 16; ++nt) acc[nt] = (floatx4){0.f, 0.f, 0.f, 0.f};

    // prologue: issue slice-0 gathers
    uintx4 ga[8], gb[8];
#pragma unroll
    for (int l = 0; l < 8; ++l)
        ga[l] = *(const uintx4*)(Tpc + goff[l]);

#pragma unroll
    for (int s = 0; s < 16; ++s) {
        if ((s & 1) == 0) {
            const int kb = s >> 1;
            // barrier 1: all waves done reading tile kb-1 (lgkmcnt(0) is ~free:
            // the MFMAs already consumed those ds_reads)
            asm volatile("s_waitcnt lgkmcnt(0)" ::: "memory");
            __builtin_amdgcn_s_barrier();
            asm volatile("" ::: "memory");
#pragma unroll
            for (int i = 0; i < 8; ++i)
                async_copy16(wsrc + kb * 64 + i * 8 * 512,
                             w2_lds + (wave * 64 + i * 8) * 64);
            // pin issue order: DMA (8) BEFORE next gathers (8), so vmcnt(8)
            // below drains exactly the DMA and leaves the gathers in flight
            asm volatile("" ::: "memory");
        }

        // distance-1 gather prefetch for slice s+1
        if (s < 15) {
            const unsigned int koff = (unsigned)(s + 1) * 64u;  // bytes
#pragma unroll
            for (int l = 0; l < 8; ++l)
                gb[l] = *(const uintx4*)(Tpc + goff[l] + koff);
        }

        // afrag from ga: tree-sum over 8 loci (dep chain 3, not 7), GELU, pack
        short8 afrag;
#pragma unroll
        for (int j = 0; j < 4; ++j) {
            float2v u0 = (float2v){bitsf(ga[0][j] << 16), bitsf(ga[0][j] & 0xFFFF0000u)};
            float2v u1 = (float2v){bitsf(ga[1][j] << 16), bitsf(ga[1][j] & 0xFFFF0000u)};
            float2v u2 = (float2v){bitsf(ga[2][j] << 16), bitsf(ga[2][j] & 0xFFFF0000u)};
            float2v u3 = (float2v){bitsf(ga[3][j] << 16), bitsf(ga[3][j] & 0xFFFF0000u)};
            float2v u4 = (float2v){bitsf(ga[4][j] << 16), bitsf(ga[4][j] & 0xFFFF0000u)};
            float2v u5 = (float2v){bitsf(ga[5][j] << 16), bitsf(ga[5][j] & 0xFFFF0000u)};
            float2v u6 = (float2v){bitsf(ga[6][j] << 16), bitsf(ga[6][j] & 0xFFFF0000u)};
            float2v u7 = (float2v){bitsf(ga[7][j] << 16), bitsf(ga[7][j] & 0xFFFF0000u)};
            float2v sj = ((u0 + u1) + (u2 + u3)) + ((u4 + u5) + (u6 + u7));
            afrag[2 * j]     = (short)f2bf_fast(gelu_fast(sj[0]));
            afrag[2 * j + 1] = (short)f2bf_fast(gelu_fast(sj[1]));
        }

        // rotate prefetch buffers (full unroll -> pure SSA renaming, no copies)
        if (s < 15) {
#pragma unroll
            for (int l = 0; l < 8; ++l) ga[l] = gb[l];
        }

        if ((s & 1) == 0) {
            // barrier 2: own DMA drained (vmcnt(8) leaves the 8 prefetched
            // gathers in flight ACROSS the barrier); after barrier all waves'
            // DMA has landed, so the tile is readable.
            asm volatile("s_waitcnt vmcnt(8)" ::: "memory");
            __builtin_amdgcn_s_barrier();
            asm volatile("" ::: "memory");
        }

        // B-frag LDS offset: row n=nt*16+p -> chunkX = (kc*4+q) ^ (p&7) (nt-free)
        const unsigned short* bbase =
            w2_lds + p * 64 + ((((s & 1) * 4 + q) ^ p7) * 8);
        __builtin_amdgcn_s_setprio(1);
#pragma unroll
        for (int nt = 0; nt < 16; ++nt) {
            short8 bfrag = *(const short8*)(bbase + nt * 1024);  // folds into ds offset
            acc[nt] = __builtin_amdgcn_mfma_f32_16x16x32_bf16(afrag, bfrag, acc[nt], 0, 0, 0);
        }
        __builtin_amdgcn_s_setprio(0);
    }

    // epilogue: D row(M=sample) = q*4+r, col(N) = nt*16+p; add b2, NT store f32
#pragma unroll
    for (int nt = 0; nt < 16; ++nt) {
        int n = nt * 16 + p;
        float b2v = b2[n];
#pragma unroll
        for (int r = 0; r < 4; ++r) {
            int m = m_base + q * 4 + r;
            __builtin_nontemporal_store(acc[nt][r] + b2v, out + m * 256 + n);
        }
    }
}

// ---------------------------------------------------------------------------
extern "C" void kernel_launch(void* const* d_in, const int* in_sizes, int n_in,
                              void* d_out, int out_size, void* d_ws, size_t ws_size,
                              hipStream_t stream) {
    const int*   hap    = (const int*)d_in[0];
    const float* tables = (const float*)d_in[1];
    const float* W1     = (const float*)d_in[2];
    const float* b1     = (const float*)d_in[3];
    const float* W2     = (const float*)d_in[4];
    const float* b2     = (const float*)d_in[5];
    float*       outp   = (float*)d_out;

    unsigned short* Tp  = (unsigned short*)d_ws;                        // 4 MB bf16
    unsigned short* W2t = (unsigned short*)d_ws + NLOCI * VOCAB * HID;  // 256 KB

    k_fuse_tables<<<dim3(512), dim3(256), 0, stream>>>(tables, W1, b1, Tp);
    k_transpose_cvt<<<dim3(8, 4), dim3(256), 0, stream>>>(W2, W2t, HID, DDIM);
    k_main<<<dim3(NSAMP / 64), dim3(256), 0, stream>>>(hap, Tp, W2t, b2, outp);
}